// Round 1
// baseline (921.913 us; speedup 1.0000x reference)
//
#include <hip/hip_runtime.h>
#include <hip/hip_bf16.h>
#include <math.h>

#define Bb 2
#define Tt 2048
#define Dd 1024
#define Hh 16
#define DKk 64

typedef __bf16 bf16_t;
typedef __bf16 bf16x8 __attribute__((ext_vector_type(8)));
typedef __bf16 bf16x4 __attribute__((ext_vector_type(4)));
typedef float f32x4 __attribute__((ext_vector_type(4)));

// async global->LDS, 16B per lane. LDS dest = wave-uniform base + lane*16.
__device__ __forceinline__ void async16(const void* gsrc, void* ldst) {
  void* g = const_cast<void*>(gsrc);
  __builtin_amdgcn_global_load_lds(
      (__attribute__((address_space(1))) void*)g,
      (__attribute__((address_space(3))) void*)ldst, 16, 0, 0);
}

__device__ __forceinline__ bf16x8 cvt8(const float4 a, const float4 b) {
  bf16x8 o;
  o[0] = (bf16_t)a.x; o[1] = (bf16_t)a.y; o[2] = (bf16_t)a.z; o[3] = (bf16_t)a.w;
  o[4] = (bf16_t)b.x; o[5] = (bf16_t)b.y; o[6] = (bf16_t)b.z; o[7] = (bf16_t)b.w;
  return o;
}

// swizzled LDS b128 fragment read: 64x64 bf16 tile, row stride 128B,
// 16B-chunk index ch (0..7) XORed with (row&7)  [T2 st-style swizzle]
#define LDSW(p, row, ch) \
  (*(const bf16x8*)((const char*)(p) + (row) * 128 + ((((ch) ^ (row)) & 7) << 4)))

// ---------------- GEMM: C[M,N] = A[M,K] @ B[N,K]^T + bias ----------------
// A, Bw, bias fp32; C bf16. (unchanged verified kernel; used for Q,K)
#define BM 128
#define BN 128
#define BK 64

__global__ __launch_bounds__(256) void gemm_f32_bt_bias(
    const float* __restrict__ A, const float* __restrict__ Bw,
    const float* __restrict__ bias, bf16_t* __restrict__ C,
    int M, int N, int K) {
  __shared__ bf16_t As[BM * BK];
  __shared__ bf16_t Bs[BN * BK];
  const int tid = threadIdx.x;
  const int lane = tid & 63;
  const int w = tid >> 6;
  const int wy = w >> 1, wx = w & 1;
  const int m0 = blockIdx.y * BM, n0 = blockIdx.x * BN;
  const int q = lane >> 4, cc = lane & 15;
  const int srow = lane >> 3;
  const int scol = (lane & 7) * 8;

  f32x4 acc[4][4] = {};

  for (int k0 = 0; k0 < K; k0 += BK) {
    __syncthreads();
#pragma unroll
    for (int i = 0; i < 4; ++i) {
      const int row = (w * 4 + i) * 8 + srow;
      const float* ap = A + (size_t)(m0 + row) * K + k0 + scol;
      const float* bp = Bw + (size_t)(n0 + row) * K + k0 + scol;
      *(bf16x8*)(As + row * BK + scol) =
          cvt8(*(const float4*)ap, *(const float4*)(ap + 4));
      *(bf16x8*)(Bs + row * BK + scol) =
          cvt8(*(const float4*)bp, *(const float4*)(bp + 4));
    }
    __syncthreads();
#pragma unroll
    for (int kk = 0; kk < 2; ++kk) {
      bf16x8 af[4], bfr[4];
#pragma unroll
      for (int i = 0; i < 4; ++i)
        af[i] = *(const bf16x8*)(As + (wy * 64 + i * 16 + cc) * BK + kk * 32 + q * 8);
#pragma unroll
      for (int j = 0; j < 4; ++j)
        bfr[j] = *(const bf16x8*)(Bs + (wx * 64 + j * 16 + cc) * BK + kk * 32 + q * 8);
#pragma unroll
      for (int i = 0; i < 4; ++i)
#pragma unroll
        for (int j = 0; j < 4; ++j)
          acc[i][j] = __builtin_amdgcn_mfma_f32_16x16x32_bf16(af[i], bfr[j], acc[i][j], 0, 0, 0);
    }
  }

#pragma unroll
  for (int j = 0; j < 4; ++j) {
    const int col = n0 + wx * 64 + j * 16 + cc;
    const float bv = bias[col];
#pragma unroll
    for (int i = 0; i < 4; ++i) {
      const int row = m0 + wy * 64 + i * 16 + q * 4;
#pragma unroll
      for (int r = 0; r < 4; ++r)
        C[(size_t)(row + r) * N + col] = (bf16_t)(acc[i][j][r] + bv);
    }
  }
}

// Same main loop; epilogue writes TRANSPOSED output for V:
// VtG[(b*H + h)*DK + dk][t]  (row len Tt).  acc[i][j][r], r=0..3 are 4
// consecutive t at fixed dk -> packed bf16x4 (8B) stores.
__global__ __launch_bounds__(256) void gemm_f32_bt_bias_vt(
    const float* __restrict__ A, const float* __restrict__ Bw,
    const float* __restrict__ bias, bf16_t* __restrict__ C,
    int M, int N, int K) {
  __shared__ bf16_t As[BM * BK];
  __shared__ bf16_t Bs[BN * BK];
  const int tid = threadIdx.x;
  const int lane = tid & 63;
  const int w = tid >> 6;
  const int wy = w >> 1, wx = w & 1;
  const int m0 = blockIdx.y * BM, n0 = blockIdx.x * BN;
  const int q = lane >> 4, cc = lane & 15;
  const int srow = lane >> 3;
  const int scol = (lane & 7) * 8;

  f32x4 acc[4][4] = {};

  for (int k0 = 0; k0 < K; k0 += BK) {
    __syncthreads();
#pragma unroll
    for (int i = 0; i < 4; ++i) {
      const int row = (w * 4 + i) * 8 + srow;
      const float* ap = A + (size_t)(m0 + row) * K + k0 + scol;
      const float* bp = Bw + (size_t)(n0 + row) * K + k0 + scol;
      *(bf16x8*)(As + row * BK + scol) =
          cvt8(*(const float4*)ap, *(const float4*)(ap + 4));
      *(bf16x8*)(Bs + row * BK + scol) =
          cvt8(*(const float4*)bp, *(const float4*)(bp + 4));
    }
    __syncthreads();
#pragma unroll
    for (int kk = 0; kk < 2; ++kk) {
      bf16x8 af[4], bfr[4];
#pragma unroll
      for (int i = 0; i < 4; ++i)
        af[i] = *(const bf16x8*)(As + (wy * 64 + i * 16 + cc) * BK + kk * 32 + q * 8);
#pragma unroll
      for (int j = 0; j < 4; ++j)
        bfr[j] = *(const bf16x8*)(Bs + (wx * 64 + j * 16 + cc) * BK + kk * 32 + q * 8);
#pragma unroll
      for (int i = 0; i < 4; ++i)
#pragma unroll
        for (int j = 0; j < 4; ++j)
          acc[i][j] = __builtin_amdgcn_mfma_f32_16x16x32_bf16(af[i], bfr[j], acc[i][j], 0, 0, 0);
    }
  }

  const int bdx = m0 >> 11;                 // batch (T=2048, BM=128 divides)
  const int t00 = (m0 & (Tt - 1)) + wy * 64;
#pragma unroll
  for (int j = 0; j < 4; ++j) {
    const int col = n0 + wx * 64 + j * 16 + cc;   // h*64 + dk
    const float bv = bias[col];
    const size_t rowbase = ((size_t)(bdx * Dd + col)) * Tt;
#pragma unroll
    for (int i = 0; i < 4; ++i) {
      const int t0 = t00 + i * 16 + q * 4;
      bf16x4 pk;
#pragma unroll
      for (int r = 0; r < 4; ++r) pk[r] = (bf16_t)(acc[i][j][r] + bv);
      *(bf16x4*)(C + rowbase + t0) = pk;
    }
  }
}

// O-projection: A bf16 (staged via global_load_lds), B fp32 (reg-cvt), C bf16.
__global__ __launch_bounds__(256) void gemm_bf16a_f32b_bias(
    const bf16_t* __restrict__ A, const float* __restrict__ Bw,
    const float* __restrict__ bias, bf16_t* __restrict__ C,
    int M, int N, int K) {
  __shared__ bf16_t As[BM * BK];
  __shared__ bf16_t Bs[BN * BK];
  const int tid = threadIdx.x;
  const int lane = tid & 63;
  const int w = tid >> 6;
  const int wy = w >> 1, wx = w & 1;
  const int m0 = blockIdx.y * BM, n0 = blockIdx.x * BN;
  const int q = lane >> 4, cc = lane & 15;
  const int srow = lane >> 3;
  const int scol = (lane & 7) * 8;

  f32x4 acc[4][4] = {};

  for (int k0 = 0; k0 < K; k0 += BK) {
    __syncthreads();
#pragma unroll
    for (int i = 0; i < 4; ++i) {     // A: 32 rows/wave via async16, linear LDS
      const int r0 = w * 32 + i * 8;
      async16(A + (size_t)(m0 + r0 + srow) * K + k0 + scol, As + r0 * BK);
    }
#pragma unroll
    for (int i = 0; i < 4; ++i) {
      const int row = (w * 4 + i) * 8 + srow;
      const float* bp = Bw + (size_t)(n0 + row) * K + k0 + scol;
      *(bf16x8*)(Bs + row * BK + scol) =
          cvt8(*(const float4*)bp, *(const float4*)(bp + 4));
    }
    __syncthreads();
#pragma unroll
    for (int kk = 0; kk < 2; ++kk) {
      bf16x8 af[4], bfr[4];
#pragma unroll
      for (int i = 0; i < 4; ++i)
        af[i] = *(const bf16x8*)(As + (wy * 64 + i * 16 + cc) * BK + kk * 32 + q * 8);
#pragma unroll
      for (int j = 0; j < 4; ++j)
        bfr[j] = *(const bf16x8*)(Bs + (wx * 64 + j * 16 + cc) * BK + kk * 32 + q * 8);
#pragma unroll
      for (int i = 0; i < 4; ++i)
#pragma unroll
        for (int j = 0; j < 4; ++j)
          acc[i][j] = __builtin_amdgcn_mfma_f32_16x16x32_bf16(af[i], bfr[j], acc[i][j], 0, 0, 0);
    }
  }

#pragma unroll
  for (int j = 0; j < 4; ++j) {
    const int col = n0 + wx * 64 + j * 16 + cc;
    const float bv = bias[col];
#pragma unroll
    for (int i = 0; i < 4; ++i) {
      const int row = m0 + wy * 64 + i * 16 + q * 4;
#pragma unroll
      for (int r = 0; r < 4; ++r)
        C[(size_t)(row + r) * N + col] = (bf16_t)(acc[i][j][r] + bv);
    }
  }
}

// ---------------- fused attention ----------------
// grid (T/64, H, B), 256 thr.  2-pass, single barrier per kt, dbuf K/V,
// T2-swizzled LDS, deferred softmax:
//   P = exp(s-C)/(exp(m-C) + sum_k exp(s_k-C)), C = 8  (shift-invariant exact)
// so the kt loop has NO cross-lane ops; reductions once after pass 1.
__global__ __launch_bounds__(256) void attn_fused(
    const bf16_t* __restrict__ Qm, const bf16_t* __restrict__ Km,
    const bf16_t* __restrict__ Vt_g,   // [B*H*DK][T] bf16 (pre-transposed)
    float* __restrict__ attn_out,      // [B,H,T,T] fp32
    bf16_t* __restrict__ Xb) {         // [B,T,D] bf16
  __shared__ bf16_t Qs[64 * 64];
  __shared__ bf16_t Ks[2][64 * 64];
  __shared__ bf16_t Vs[2][64 * 64];    // V^T tile: [d][k]
  __shared__ bf16_t Ps[64 * 64];

  const int tid = threadIdx.x;
  const int lane = tid & 63;
  const int w = tid >> 6;
  const int qt = blockIdx.x, h = blockIdx.y, b = blockIdx.z;
  const int q = lane >> 4, cc = lane & 15;
  const size_t base = (size_t)b * Tt * Dd + (size_t)h * DKk;
  const size_t vbase = ((size_t)(b * Hh + h) * DKk) * Tt;
  const int srow = lane >> 3;                       // 0..7 within 8-row slab
  const int gcol = ((lane & 7) ^ srow) * 8;         // pre-swizzled src chunk (elems)
  const float CL = 0.18033688f;   // 0.125 * log2(e)
  const float C2 = 11.54156028f;  // 8 * log2(e)

  // prologue: stage Q tile + K tile 0 (swizzled via pre-swizzled global col)
#pragma unroll
  for (int i = 0; i < 2; ++i) {
    const int r0 = w * 16 + i * 8;
    async16(Qm + base + (size_t)(qt * 64 + r0 + srow) * Dd + gcol, Qs + r0 * 64);
    async16(Km + base + (size_t)(r0 + srow) * Dd + gcol, Ks[0] + r0 * 64);
  }

  float Mp[4], Lp[4];
#pragma unroll
  for (int r = 0; r < 4; ++r) { Mp[r] = -3.0e38f; Lp[r] = 0.f; }

  // ---- pass 1: per-lane max / sum-exp only (no cross-lane work) ----
  for (int kt = 0; kt < 32; ++kt) {
    __syncthreads();
    if (kt < 31) {
      bf16_t* kd = Ks[(kt + 1) & 1];
#pragma unroll
      for (int i = 0; i < 2; ++i) {
        const int r0 = w * 16 + i * 8;
        async16(Km + base + (size_t)((kt + 1) * 64 + r0 + srow) * Dd + gcol, kd + r0 * 64);
      }
    }
    const bf16_t* kc = Ks[kt & 1];
    f32x4 acc[4] = {};
    __builtin_amdgcn_s_setprio(1);
#pragma unroll
    for (int kk = 0; kk < 2; ++kk) {
      const bf16x8 af = LDSW(Qs, w * 16 + cc, kk * 4 + q);
#pragma unroll
      for (int j = 0; j < 4; ++j) {
        const bf16x8 bfr = LDSW(kc, j * 16 + cc, kk * 4 + q);
        acc[j] = __builtin_amdgcn_mfma_f32_16x16x32_bf16(af, bfr, acc[j], 0, 0, 0);
      }
    }
    __builtin_amdgcn_s_setprio(0);
#pragma unroll
    for (int r = 0; r < 4; ++r) {
      Mp[r] = fmaxf(Mp[r], fmaxf(fmaxf(acc[0][r], acc[1][r]),
                                 fmaxf(acc[2][r], acc[3][r])));
      Lp[r] += exp2f(fmaf(acc[0][r], CL, -C2)) + exp2f(fmaf(acc[1][r], CL, -C2)) +
               exp2f(fmaf(acc[2][r], CL, -C2)) + exp2f(fmaf(acc[3][r], CL, -C2));
    }
  }

  // one-time 16-lane reductions; inv = 1/(exp(m-8) + sum exp(s-8))
  float inv1[4];
#pragma unroll
  for (int r = 0; r < 4; ++r) {
    float mx = Mp[r];
#pragma unroll
    for (int msk = 1; msk < 16; msk <<= 1) mx = fmaxf(mx, __shfl_xor(mx, msk));
    float ls = Lp[r];
#pragma unroll
    for (int msk = 1; msk < 16; msk <<= 1) ls += __shfl_xor(ls, msk);
    inv1[r] = 1.0f / (exp2f(fmaf(mx, CL, -C2)) + ls);
  }

  // prologue pass 2: K tile 0 + V^T tile 0
#pragma unroll
  for (int i = 0; i < 2; ++i) {
    const int r0 = w * 16 + i * 8;
    async16(Km + base + (size_t)(r0 + srow) * Dd + gcol, Ks[0] + r0 * 64);
    async16(Vt_g + vbase + (size_t)(r0 + srow) * Tt + gcol, Vs[0] + r0 * 64);
  }

  f32x4 xacc[4] = {};
  const size_t arowbase = ((size_t)(b * Hh + h) * Tt + (size_t)qt * 64) * Tt;

  // ---- pass 2: recompute S, write attn, PV ----
  for (int kt = 0; kt < 32; ++kt) {
    __syncthreads();
    if (kt < 31) {
      bf16_t* kd = Ks[(kt + 1) & 1];
      bf16_t* vd = Vs[(kt + 1) & 1];
#pragma unroll
      for (int i = 0; i < 2; ++i) {
        const int r0 = w * 16 + i * 8;
        async16(Km + base + (size_t)((kt + 1) * 64 + r0 + srow) * Dd + gcol, kd + r0 * 64);
        async16(Vt_g + vbase + (size_t)(r0 + srow) * Tt + (kt + 1) * 64 + gcol, vd + r0 * 64);
      }
    }
    const bf16_t* kc = Ks[kt & 1];
    const bf16_t* vc = Vs[kt & 1];

    f32x4 acc[4] = {};
    __builtin_amdgcn_s_setprio(1);
#pragma unroll
    for (int kk = 0; kk < 2; ++kk) {
      const bf16x8 af = LDSW(Qs, w * 16 + cc, kk * 4 + q);
#pragma unroll
      for (int j = 0; j < 4; ++j) {
        const bf16x8 bfr = LDSW(kc, j * 16 + cc, kk * 4 + q);
        acc[j] = __builtin_amdgcn_mfma_f32_16x16x32_bf16(af, bfr, acc[j], 0, 0, 0);
      }
    }
    __builtin_amdgcn_s_setprio(0);

    // P phase: fp32 attn store + swizzled bf16 Ps write (wave-local rows)
#pragma unroll
    for (int j = 0; j < 4; ++j) {
      const int pcol = j * 16 + cc;
#pragma unroll
      for (int r = 0; r < 4; ++r) {
        const int prow = w * 16 + q * 4 + r;
        const float p = exp2f(fmaf(acc[j][r], CL, -C2)) * inv1[r];
        attn_out[arowbase + (size_t)prow * Tt + kt * 64 + pcol] = p;
        *(bf16_t*)((char*)Ps + prow * 128 + ((pcol * 2) ^ ((prow & 7) << 4))) = (bf16_t)p;
      }
    }

    // PV (Ps rows are wave-local: no barrier needed, lgkmcnt ordering only)
    __builtin_amdgcn_s_setprio(1);
#pragma unroll
    for (int kk = 0; kk < 2; ++kk) {
      const bf16x8 af = LDSW(Ps, w * 16 + cc, kk * 4 + q);
#pragma unroll
      for (int j = 0; j < 4; ++j) {
        const bf16x8 bfr = LDSW(vc, j * 16 + cc, kk * 4 + q);
        xacc[j] = __builtin_amdgcn_mfma_f32_16x16x32_bf16(af, bfr, xacc[j], 0, 0, 0);
      }
    }
    __builtin_amdgcn_s_setprio(0);
  }

#pragma unroll
  for (int j = 0; j < 4; ++j)
#pragma unroll
    for (int r = 0; r < 4; ++r) {
      const int row = qt * 64 + w * 16 + q * 4 + r;
      Xb[base + (size_t)row * Dd + j * 16 + cc] = (bf16_t)xacc[j][r];
    }
}

// ---------------- residual + LayerNorm (fp32 out) ----------------
__global__ __launch_bounds__(256) void ln_kernel(
    const float* __restrict__ resid, const bf16_t* __restrict__ O,
    const float* __restrict__ gamma, const float* __restrict__ beta,
    float* __restrict__ out) {
  const int row = blockIdx.x;
  const int tid = threadIdx.x;
  const size_t roff = (size_t)row * Dd + tid * 4;
  const float4 rv = *(const float4*)(resid + roff);
  const bf16x4 ov = *(const bf16x4*)(O + roff);
  const float y0 = rv.x + (float)ov.x;
  const float y1 = rv.y + (float)ov.y;
  const float y2 = rv.z + (float)ov.z;
  const float y3 = rv.w + (float)ov.w;
  float s = y0 + y1 + y2 + y3;
  float s2 = y0 * y0 + y1 * y1 + y2 * y2 + y3 * y3;
#pragma unroll
  for (int msk = 1; msk < 64; msk <<= 1) {
    s += __shfl_xor(s, msk);
    s2 += __shfl_xor(s2, msk);
  }
  __shared__ float red[8];
  const int w = tid >> 6;
  if ((tid & 63) == 0) { red[w] = s; red[4 + w] = s2; }
  __syncthreads();
  s = red[0] + red[1] + red[2] + red[3];
  s2 = red[4] + red[5] + red[6] + red[7];
  const float mu = s * (1.f / Dd);
  const float rstd = rsqrtf(s2 * (1.f / Dd) - mu * mu + 1e-5f);
  const float4 gv = *(const float4*)(gamma + tid * 4);
  const float4 bv = *(const float4*)(beta + tid * 4);
  float4 o;
  o.x = (y0 - mu) * rstd * gv.x + bv.x;
  o.y = (y1 - mu) * rstd * gv.y + bv.y;
  o.z = (y2 - mu) * rstd * gv.z + bv.z;
  o.w = (y3 - mu) * rstd * gv.w + bv.w;
  *(float4*)(out + roff) = o;
}

extern "C" void kernel_launch(void* const* d_in, const int* in_sizes, int n_in,
                              void* d_out, int out_size, void* d_ws, size_t ws_size,
                              hipStream_t stream) {
  const float* query = (const float*)d_in[0];
  const float* key = (const float*)d_in[1];
  const float* value = (const float*)d_in[2];
  const float* Wq = (const float*)d_in[3];
  const float* bq = (const float*)d_in[4];
  const float* Wk = (const float*)d_in[5];
  const float* bk = (const float*)d_in[6];
  const float* Wv = (const float*)d_in[7];
  const float* bv = (const float*)d_in[8];
  const float* Wo = (const float*)d_in[9];
  const float* bo = (const float*)d_in[10];
  const float* gamma = (const float*)d_in[11];
  const float* beta = (const float*)d_in[12];

  float* y_out = (float*)d_out;                       // [B,T,D] fp32
  float* attn_out = y_out + (size_t)Bb * Tt * Dd;     // [B,H,T,T] fp32

  // workspace: 5x bf16 [B,T,D] = 40MB
  char* p = (char*)d_ws;
  const size_t nTD = (size_t)Bb * Tt * Dd;  // 4,194,304
  bf16_t* Qb = (bf16_t*)p;  p += nTD * 2;
  bf16_t* Kb = (bf16_t*)p;  p += nTD * 2;
  bf16_t* VtG = (bf16_t*)p; p += nTD * 2;   // [B*H*DK][T]
  bf16_t* Xb = (bf16_t*)p;  p += nTD * 2;
  bf16_t* Ob = (bf16_t*)p;  p += nTD * 2;

  dim3 gg(Dd / BN, (Bb * Tt) / BM);  // (8, 32)
  gemm_f32_bt_bias<<<gg, 256, 0, stream>>>(query, Wq, bq, Qb, Bb * Tt, Dd, Dd);
  gemm_f32_bt_bias<<<gg, 256, 0, stream>>>(key, Wk, bk, Kb, Bb * Tt, Dd, Dd);
  gemm_f32_bt_bias_vt<<<gg, 256, 0, stream>>>(value, Wv, bv, VtG, Bb * Tt, Dd, Dd);

  dim3 ga(Tt / 64, Hh, Bb);  // (32, 16, 2)
  attn_fused<<<ga, 256, 0, stream>>>(Qb, Kb, VtG, attn_out, Xb);

  gemm_bf16a_f32b_bias<<<gg, 256, 0, stream>>>(Xb, Wo, bo, Ob, Bb * Tt, Dd, Dd);

  ln_kernel<<<Bb * Tt, 256, 0, stream>>>(query, Ob, gamma, beta, y_out);
}

// Round 2
// 911.677 us; speedup vs baseline: 1.0112x; 1.0112x over previous
//
#include <hip/hip_runtime.h>
#include <hip/hip_bf16.h>
#include <math.h>

#define Bb 2
#define Tt 2048
#define Dd 1024
#define Hh 16
#define DKk 64

typedef __bf16 bf16_t;
typedef __bf16 bf16x8 __attribute__((ext_vector_type(8)));
typedef __bf16 bf16x4 __attribute__((ext_vector_type(4)));
typedef float f32x4 __attribute__((ext_vector_type(4)));

// async global->LDS, 16B per lane. LDS dest = wave-uniform base + lane*16.
__device__ __forceinline__ void async16(const void* gsrc, void* ldst) {
  void* g = const_cast<void*>(gsrc);
  __builtin_amdgcn_global_load_lds(
      (__attribute__((address_space(1))) void*)g,
      (__attribute__((address_space(3))) void*)ldst, 16, 0, 0);
}

__device__ __forceinline__ bf16x8 cvt8(const float4 a, const float4 b) {
  bf16x8 o;
  o[0] = (bf16_t)a.x; o[1] = (bf16_t)a.y; o[2] = (bf16_t)a.z; o[3] = (bf16_t)a.w;
  o[4] = (bf16_t)b.x; o[5] = (bf16_t)b.y; o[6] = (bf16_t)b.z; o[7] = (bf16_t)b.w;
  return o;
}

// swizzled LDS b128 fragment read: 64x64 bf16 tile, row stride 128B,
// 16B-chunk index ch (0..7) XORed with (row&7)  [T2 st-style swizzle]
#define LDSW(p, row, ch) \
  (*(const bf16x8*)((const char*)(p) + (row) * 128 + ((((ch) ^ (row)) & 7) << 4)))

// ---------------- GEMMs: C[M,N] = A[M,K] @ B[N,K]^T + bias ----------------
// BM=64 x BN=128 tiles -> grid (8,64,z): 512-1536 blocks (vs 256 before) so
// multiple blocks/CU overlap the 2-phase barrier drains.
#define GM 4096
#define GN 1024
#define GK 1024
#define BM2 64
#define BN2 128
#define BK2 64

// Fused Q/K/V projections: blockIdx.z selects the problem. z==2 (V) writes
// the output TRANSPOSED: Vt[(b*H+h)*DK + dk][t], for coalesced attn staging.
__global__ __launch_bounds__(256) void gemm_qkv(
    const float* __restrict__ Aq, const float* __restrict__ Ak,
    const float* __restrict__ Av, const float* __restrict__ Wqp,
    const float* __restrict__ Wkp, const float* __restrict__ Wvp,
    const float* __restrict__ bqp, const float* __restrict__ bkp,
    const float* __restrict__ bvp, bf16_t* __restrict__ Cq,
    bf16_t* __restrict__ Ck, bf16_t* __restrict__ Cv) {
  __shared__ bf16_t As[BM2 * BK2];
  __shared__ bf16_t Bs[BN2 * BK2];
  const int z = blockIdx.z;
  const float* A = (z == 0) ? Aq : (z == 1) ? Ak : Av;
  const float* Bw = (z == 0) ? Wqp : (z == 1) ? Wkp : Wvp;
  const float* bias = (z == 0) ? bqp : (z == 1) ? bkp : bvp;

  const int tid = threadIdx.x;
  const int lane = tid & 63;
  const int w = tid >> 6;
  const int wy = w >> 1, wx = w & 1;
  const int m0 = blockIdx.y * BM2, n0 = blockIdx.x * BN2;
  const int q = lane >> 4, cc = lane & 15;
  const int srow = lane >> 3;
  const int scol = (lane & 7) * 8;

  f32x4 acc[2][4] = {};

  for (int k0 = 0; k0 < GK; k0 += BK2) {
    __syncthreads();
#pragma unroll
    for (int i = 0; i < 2; ++i) {      // A: 16 rows/wave
      const int row = w * 16 + i * 8 + srow;
      const float* ap = A + (size_t)(m0 + row) * GK + k0 + scol;
      *(bf16x8*)(As + row * BK2 + scol) =
          cvt8(*(const float4*)ap, *(const float4*)(ap + 4));
    }
#pragma unroll
    for (int i = 0; i < 4; ++i) {      // B: 32 rows/wave
      const int row = (w * 4 + i) * 8 + srow;
      const float* bp = Bw + (size_t)(n0 + row) * GK + k0 + scol;
      *(bf16x8*)(Bs + row * BK2 + scol) =
          cvt8(*(const float4*)bp, *(const float4*)(bp + 4));
    }
    __syncthreads();
#pragma unroll
    for (int kk = 0; kk < 2; ++kk) {
      bf16x8 af[2], bfr[4];
#pragma unroll
      for (int i = 0; i < 2; ++i)
        af[i] = *(const bf16x8*)(As + (wy * 32 + i * 16 + cc) * BK2 + kk * 32 + q * 8);
#pragma unroll
      for (int j = 0; j < 4; ++j)
        bfr[j] = *(const bf16x8*)(Bs + (wx * 64 + j * 16 + cc) * BK2 + kk * 32 + q * 8);
#pragma unroll
      for (int i = 0; i < 2; ++i)
#pragma unroll
        for (int j = 0; j < 4; ++j)
          acc[i][j] = __builtin_amdgcn_mfma_f32_16x16x32_bf16(af[i], bfr[j], acc[i][j], 0, 0, 0);
    }
  }

  if (z < 2) {
    bf16_t* C = z ? Ck : Cq;
#pragma unroll
    for (int j = 0; j < 4; ++j) {
      const int col = n0 + wx * 64 + j * 16 + cc;
      const float bv = bias[col];
#pragma unroll
      for (int i = 0; i < 2; ++i) {
        const int row = m0 + wy * 32 + i * 16 + q * 4;
#pragma unroll
        for (int r = 0; r < 4; ++r)
          C[(size_t)(row + r) * GN + col] = (bf16_t)(acc[i][j][r] + bv);
      }
    }
  } else {
    const int bdx = m0 >> 11;
    const int t00 = (m0 & (Tt - 1)) + wy * 32;
#pragma unroll
    for (int j = 0; j < 4; ++j) {
      const int col = n0 + wx * 64 + j * 16 + cc;   // h*64 + dk
      const float bv = bias[col];
      const size_t rowbase = ((size_t)(bdx * Dd + col)) * Tt;
#pragma unroll
      for (int i = 0; i < 2; ++i) {
        const int t0 = t00 + i * 16 + q * 4;
        bf16x4 pk;
#pragma unroll
        for (int r = 0; r < 4; ++r) pk[r] = (bf16_t)(acc[i][j][r] + bv);
        *(bf16x4*)(Cv + rowbase + t0) = pk;
      }
    }
  }
}

// O-projection: A bf16 (staged via global_load_lds), B fp32, C bf16.
__global__ __launch_bounds__(256) void gemm_obf16(
    const bf16_t* __restrict__ A, const float* __restrict__ Bw,
    const float* __restrict__ bias, bf16_t* __restrict__ C) {
  __shared__ bf16_t As[BM2 * BK2];
  __shared__ bf16_t Bs[BN2 * BK2];
  const int tid = threadIdx.x;
  const int lane = tid & 63;
  const int w = tid >> 6;
  const int wy = w >> 1, wx = w & 1;
  const int m0 = blockIdx.y * BM2, n0 = blockIdx.x * BN2;
  const int q = lane >> 4, cc = lane & 15;
  const int srow = lane >> 3;
  const int scol = (lane & 7) * 8;

  f32x4 acc[2][4] = {};

  for (int k0 = 0; k0 < GK; k0 += BK2) {
    __syncthreads();
#pragma unroll
    for (int i = 0; i < 2; ++i) {      // A: async 8-row slabs, linear LDS
      const int r0 = w * 16 + i * 8;
      async16(A + (size_t)(m0 + r0 + srow) * GK + k0 + scol, As + r0 * BK2);
    }
#pragma unroll
    for (int i = 0; i < 4; ++i) {
      const int row = (w * 4 + i) * 8 + srow;
      const float* bp = Bw + (size_t)(n0 + row) * GK + k0 + scol;
      *(bf16x8*)(Bs + row * BK2 + scol) =
          cvt8(*(const float4*)bp, *(const float4*)(bp + 4));
    }
    __syncthreads();
#pragma unroll
    for (int kk = 0; kk < 2; ++kk) {
      bf16x8 af[2], bfr[4];
#pragma unroll
      for (int i = 0; i < 2; ++i)
        af[i] = *(const bf16x8*)(As + (wy * 32 + i * 16 + cc) * BK2 + kk * 32 + q * 8);
#pragma unroll
      for (int j = 0; j < 4; ++j)
        bfr[j] = *(const bf16x8*)(Bs + (wx * 64 + j * 16 + cc) * BK2 + kk * 32 + q * 8);
#pragma unroll
      for (int i = 0; i < 2; ++i)
#pragma unroll
        for (int j = 0; j < 4; ++j)
          acc[i][j] = __builtin_amdgcn_mfma_f32_16x16x32_bf16(af[i], bfr[j], acc[i][j], 0, 0, 0);
    }
  }

#pragma unroll
  for (int j = 0; j < 4; ++j) {
    const int col = n0 + wx * 64 + j * 16 + cc;
    const float bv = bias[col];
#pragma unroll
    for (int i = 0; i < 2; ++i) {
      const int row = m0 + wy * 32 + i * 16 + q * 4;
#pragma unroll
      for (int r = 0; r < 4; ++r)
        C[(size_t)(row + r) * GN + col] = (bf16_t)(acc[i][j][r] + bv);
    }
  }
}

// ---------------- fused attention ----------------
// grid (T/64, H, B), 256 thr.  2-pass, single top barrier per kt, dbuf K/V,
// T2-swizzled LDS, deferred softmax (shift C=8, exact).
// Pass 2: after QK^T the retired K buffer (8KB) is reused as a per-wave fp32
// S half-tile (32 cols at a time): coalesced dwordx4 attn stores + PV A-frag
// read from it (same bf16 rounding as before). LDS = 40KB -> 4 blocks/CU.
__global__ __launch_bounds__(256) void attn_fused(
    const bf16_t* __restrict__ Qm, const bf16_t* __restrict__ Km,
    const bf16_t* __restrict__ Vt_g,   // [B*H*DK][T] bf16 (pre-transposed)
    float* __restrict__ attn_out,      // [B,H,T,T] fp32
    bf16_t* __restrict__ Xb) {         // [B,T,D] bf16
  __shared__ bf16_t Qs[64 * 64];
  __shared__ bf16_t Ks[2][64 * 64];
  __shared__ bf16_t Vs[2][64 * 64];    // V^T tile: [d][k]

  const int tid = threadIdx.x;
  const int lane = tid & 63;
  const int w = tid >> 6;
  const int qt = blockIdx.x, h = blockIdx.y, b = blockIdx.z;
  const int q = lane >> 4, cc = lane & 15;
  const size_t base = (size_t)b * Tt * Dd + (size_t)h * DKk;
  const size_t vbase = ((size_t)(b * Hh + h) * DKk) * Tt;
  const int srow = lane >> 3;                   // 0..7 within 8-row slab
  const int gcol = ((lane & 7) ^ srow) * 8;     // pre-swizzled src chunk (elems)
  const int l2 = lane >> 2;                     // 0..15: row16 for readback
  const int lc = lane & 3;                      // chunk base for readback
  const float CL = 0.18033688f;   // 0.125 * log2(e)
  const float C2 = 11.54156028f;  // 8 * log2(e)

  // prologue: stage Q tile + K tile 0
#pragma unroll
  for (int i = 0; i < 2; ++i) {
    const int r0 = w * 16 + i * 8;
    async16(Qm + base + (size_t)(qt * 64 + r0 + srow) * Dd + gcol, Qs + r0 * 64);
    async16(Km + base + (size_t)(r0 + srow) * Dd + gcol, Ks[0] + r0 * 64);
  }

  float Mp[4], Lp[4];
#pragma unroll
  for (int r = 0; r < 4; ++r) { Mp[r] = -3.0e38f; Lp[r] = 0.f; }

  // ---- pass 1: per-lane max / sum-exp only ----
  for (int kt = 0; kt < 32; ++kt) {
    __syncthreads();
    if (kt < 31) {
      bf16_t* kd = Ks[(kt + 1) & 1];
#pragma unroll
      for (int i = 0; i < 2; ++i) {
        const int r0 = w * 16 + i * 8;
        async16(Km + base + (size_t)((kt + 1) * 64 + r0 + srow) * Dd + gcol, kd + r0 * 64);
      }
    }
    const bf16_t* kc = Ks[kt & 1];
    f32x4 acc[4] = {};
    __builtin_amdgcn_s_setprio(1);
#pragma unroll
    for (int kk = 0; kk < 2; ++kk) {
      const bf16x8 af = LDSW(Qs, w * 16 + cc, kk * 4 + q);
#pragma unroll
      for (int j = 0; j < 4; ++j) {
        const bf16x8 bfr = LDSW(kc, j * 16 + cc, kk * 4 + q);
        acc[j] = __builtin_amdgcn_mfma_f32_16x16x32_bf16(af, bfr, acc[j], 0, 0, 0);
      }
    }
    __builtin_amdgcn_s_setprio(0);
#pragma unroll
    for (int r = 0; r < 4; ++r) {
      Mp[r] = fmaxf(Mp[r], fmaxf(fmaxf(acc[0][r], acc[1][r]),
                                 fmaxf(acc[2][r], acc[3][r])));
      Lp[r] += exp2f(fmaf(acc[0][r], CL, -C2)) + exp2f(fmaf(acc[1][r], CL, -C2)) +
               exp2f(fmaf(acc[2][r], CL, -C2)) + exp2f(fmaf(acc[3][r], CL, -C2));
    }
  }

  float inv1[4];
#pragma unroll
  for (int r = 0; r < 4; ++r) {
    float mx = Mp[r];
#pragma unroll
    for (int msk = 1; msk < 16; msk <<= 1) mx = fmaxf(mx, __shfl_xor(mx, msk));
    float ls = Lp[r];
#pragma unroll
    for (int msk = 1; msk < 16; msk <<= 1) ls += __shfl_xor(ls, msk);
    inv1[r] = 1.0f / (exp2f(fmaf(mx, CL, -C2)) + ls);
  }

  // prologue pass 2: K tile 0 + V^T tile 0
#pragma unroll
  for (int i = 0; i < 2; ++i) {
    const int r0 = w * 16 + i * 8;
    async16(Km + base + (size_t)(r0 + srow) * Dd + gcol, Ks[0] + r0 * 64);
    async16(Vt_g + vbase + (size_t)(r0 + srow) * Tt + gcol, Vs[0] + r0 * 64);
  }

  f32x4 xacc[4] = {};
  const size_t arowbase = ((size_t)(b * Hh + h) * Tt + (size_t)qt * 64) * Tt;

  // ---- pass 2 ----
  for (int kt = 0; kt < 32; ++kt) {
    __syncthreads();
    if (kt < 31) {
      bf16_t* kd = Ks[(kt + 1) & 1];
      bf16_t* vd = Vs[(kt + 1) & 1];
#pragma unroll
      for (int i = 0; i < 2; ++i) {
        const int r0 = w * 16 + i * 8;
        async16(Km + base + (size_t)((kt + 1) * 64 + r0 + srow) * Dd + gcol, kd + r0 * 64);
        async16(Vt_g + vbase + (size_t)(r0 + srow) * Tt + (kt + 1) * 64 + gcol, vd + r0 * 64);
      }
    }
    const bf16_t* kc = Ks[kt & 1];
    const bf16_t* vc = Vs[kt & 1];

    f32x4 acc[4] = {};
    __builtin_amdgcn_s_setprio(1);
#pragma unroll
    for (int kk = 0; kk < 2; ++kk) {
      const bf16x8 af = LDSW(Qs, w * 16 + cc, kk * 4 + q);
#pragma unroll
      for (int j = 0; j < 4; ++j) {
        const bf16x8 bfr = LDSW(kc, j * 16 + cc, kk * 4 + q);
        acc[j] = __builtin_amdgcn_mfma_f32_16x16x32_bf16(af, bfr, acc[j], 0, 0, 0);
      }
    }
    __builtin_amdgcn_s_setprio(0);

    // rendezvous: all waves finished reading kc. Raw barrier (NO vmcnt drain:
    // prefetch stays in flight). Reads are complete (lgkmcnt before MFMA).
    __builtin_amdgcn_sched_barrier(0);
    __builtin_amdgcn_s_barrier();

    // per-wave fp32 S stripe in the retired kc buffer:
    // stripe = kc + w*2048, layout [16 rows][32 f32], byte swizzle
    // lb ^ ((row16&7)<<4) at 16B granularity (2-way conflicts max).
    char* sfw = (char*)(&Ks[kt & 1][0]) + w * 2048;
#pragma unroll
    for (int half = 0; half < 2; ++half) {
      // write 8 S values (cols half*32 .. +31)
#pragma unroll
      for (int jj = 0; jj < 2; ++jj) {
        const int j = half * 2 + jj;
#pragma unroll
        for (int r = 0; r < 4; ++r) {
          const int row16 = q * 4 + r;
          const float p = exp2f(fmaf(acc[j][r], CL, -C2)) * inv1[r];
          *(float*)(sfw + row16 * 128 +
                    (((jj * 16 + cc) * 4) ^ ((row16 & 7) << 4))) = p;
        }
      }
      // coalesced readback + dwordx4 attn store (own stripe, DS in-order)
#pragma unroll
      for (int s = 0; s < 2; ++s) {
        const int ch = lc + 4 * s;  // 16B chunk 0..7 within 128B row
        const f32x4 v = *(const f32x4*)(sfw + l2 * 128 +
                                        ((ch * 16) ^ ((l2 & 7) << 4)));
        const int prow = w * 16 + l2;
        *(f32x4*)(attn_out + arowbase + (size_t)prow * Tt + kt * 64 +
                  half * 32 + ch * 4) = v;
      }
      // PV for kk = half: A-frag from fp32 stripe (row = cc), cvt to bf16
      const char* p0 = sfw + cc * 128;
      const f32x4 a = *(const f32x4*)(p0 + ((q * 32) ^ ((cc & 7) << 4)));
      const f32x4 bb = *(const f32x4*)(p0 + ((q * 32 + 16) ^ ((cc & 7) << 4)));
      bf16x8 af;
      af[0] = (bf16_t)a[0]; af[1] = (bf16_t)a[1];
      af[2] = (bf16_t)a[2]; af[3] = (bf16_t)a[3];
      af[4] = (bf16_t)bb[0]; af[5] = (bf16_t)bb[1];
      af[6] = (bf16_t)bb[2]; af[7] = (bf16_t)bb[3];
      __builtin_amdgcn_s_setprio(1);
#pragma unroll
      for (int j = 0; j < 4; ++j) {
        const bf16x8 bfr = LDSW(vc, j * 16 + cc, half * 4 + q);
        xacc[j] = __builtin_amdgcn_mfma_f32_16x16x32_bf16(af, bfr, xacc[j], 0, 0, 0);
      }
      __builtin_amdgcn_s_setprio(0);
    }
  }

#pragma unroll
  for (int j = 0; j < 4; ++j)
#pragma unroll
    for (int r = 0; r < 4; ++r) {
      const int row = qt * 64 + w * 16 + q * 4 + r;
      Xb[base + (size_t)row * Dd + j * 16 + cc] = (bf16_t)xacc[j][r];
    }
}

// ---------------- residual + LayerNorm (fp32 out) ----------------
__global__ __launch_bounds__(256) void ln_kernel(
    const float* __restrict__ resid, const bf16_t* __restrict__ O,
    const float* __restrict__ gamma, const float* __restrict__ beta,
    float* __restrict__ out) {
  const int row = blockIdx.x;
  const int tid = threadIdx.x;
  const size_t roff = (size_t)row * Dd + tid * 4;
  const float4 rv = *(const float4*)(resid + roff);
  const bf16x4 ov = *(const bf16x4*)(O + roff);
  const float y0 = rv.x + (float)ov.x;
  const float y1 = rv.y + (float)ov.y;
  const float y2 = rv.z + (float)ov.z;
  const float y3 = rv.w + (float)ov.w;
  float s = y0 + y1 + y2 + y3;
  float s2 = y0 * y0 + y1 * y1 + y2 * y2 + y3 * y3;
#pragma unroll
  for (int msk = 1; msk < 64; msk <<= 1) {
    s += __shfl_xor(s, msk);
    s2 += __shfl_xor(s2, msk);
  }
  __shared__ float red[8];
  const int w = tid >> 6;
  if ((tid & 63) == 0) { red[w] = s; red[4 + w] = s2; }
  __syncthreads();
  s = red[0] + red[1] + red[2] + red[3];
  s2 = red[4] + red[5] + red[6] + red[7];
  const float mu = s * (1.f / Dd);
  const float rstd = rsqrtf(s2 * (1.f / Dd) - mu * mu + 1e-5f);
  const float4 gv = *(const float4*)(gamma + tid * 4);
  const float4 bv = *(const float4*)(beta + tid * 4);
  float4 o;
  o.x = (y0 - mu) * rstd * gv.x + bv.x;
  o.y = (y1 - mu) * rstd * gv.y + bv.y;
  o.z = (y2 - mu) * rstd * gv.z + bv.z;
  o.w = (y3 - mu) * rstd * gv.w + bv.w;
  *(float4*)(out + roff) = o;
}

extern "C" void kernel_launch(void* const* d_in, const int* in_sizes, int n_in,
                              void* d_out, int out_size, void* d_ws, size_t ws_size,
                              hipStream_t stream) {
  const float* query = (const float*)d_in[0];
  const float* key = (const float*)d_in[1];
  const float* value = (const float*)d_in[2];
  const float* Wq = (const float*)d_in[3];
  const float* bq = (const float*)d_in[4];
  const float* Wk = (const float*)d_in[5];
  const float* bk = (const float*)d_in[6];
  const float* Wv = (const float*)d_in[7];
  const float* bv = (const float*)d_in[8];
  const float* Wo = (const float*)d_in[9];
  const float* bo = (const float*)d_in[10];
  const float* gamma = (const float*)d_in[11];
  const float* beta = (const float*)d_in[12];

  float* y_out = (float*)d_out;                       // [B,T,D] fp32
  float* attn_out = y_out + (size_t)Bb * Tt * Dd;     // [B,H,T,T] fp32

  // workspace: 5x bf16 [B,T,D] = 40MB
  char* p = (char*)d_ws;
  const size_t nTD = (size_t)Bb * Tt * Dd;  // 4,194,304
  bf16_t* Qb = (bf16_t*)p;  p += nTD * 2;
  bf16_t* Kb = (bf16_t*)p;  p += nTD * 2;
  bf16_t* VtG = (bf16_t*)p; p += nTD * 2;   // [B*H*DK][T]
  bf16_t* Xb = (bf16_t*)p;  p += nTD * 2;
  bf16_t* Ob = (bf16_t*)p;  p += nTD * 2;

  dim3 gqkv(GN / BN2, GM / BM2, 3);  // (8, 64, 3) = 1536 blocks
  gemm_qkv<<<gqkv, 256, 0, stream>>>(query, key, value, Wq, Wk, Wv,
                                     bq, bk, bv, Qb, Kb, VtG);

  dim3 ga(Tt / 64, Hh, Bb);  // (32, 16, 2)
  attn_fused<<<ga, 256, 0, stream>>>(Qb, Kb, VtG, attn_out, Xb);

  dim3 go(GN / BN2, GM / BM2);  // (8, 64) = 512 blocks
  gemm_obf16<<<go, 256, 0, stream>>>(Xb, Wo, bo, Ob);

  ln_kernel<<<Bb * Tt, 256, 0, stream>>>(query, Ob, gamma, beta, y_out);
}

// Round 7
// 843.719 us; speedup vs baseline: 1.0927x; 1.0805x over previous
//
#include <hip/hip_runtime.h>
#include <hip/hip_bf16.h>
#include <math.h>

#define Bb 2
#define Tt 2048
#define Dd 1024
#define Hh 16
#define DKk 64

typedef __bf16 bf16_t;
typedef __bf16 bf16x8 __attribute__((ext_vector_type(8)));
typedef __bf16 bf16x4 __attribute__((ext_vector_type(4)));
typedef float f32x4 __attribute__((ext_vector_type(4)));

// async global->LDS, 16B per lane. LDS dest = wave-uniform base + lane*16.
__device__ __forceinline__ void async16(const void* gsrc, void* ldst) {
  void* g = const_cast<void*>(gsrc);
  __builtin_amdgcn_global_load_lds(
      (__attribute__((address_space(1))) void*)g,
      (__attribute__((address_space(3))) void*)ldst, 16, 0, 0);
}

__device__ __forceinline__ bf16x8 cvt8(const float4 a, const float4 b) {
  bf16x8 o;
  o[0] = (bf16_t)a.x; o[1] = (bf16_t)a.y; o[2] = (bf16_t)a.z; o[3] = (bf16_t)a.w;
  o[4] = (bf16_t)b.x; o[5] = (bf16_t)b.y; o[6] = (bf16_t)b.z; o[7] = (bf16_t)b.w;
  return o;
}

// swizzled LDS b128 fragment read: 64x64 bf16 tile, row stride 128B,
// 16B-chunk index ch (0..7) XORed with (row&7)  [T2 st-style swizzle]
#define LDSW(p, row, ch) \
  (*(const bf16x8*)((const char*)(p) + (row) * 128 + ((((ch) ^ (row)) & 7) << 4)))

// ---------------- fp32 -> bf16 conversion (inputs + weights) ----------------
// grid 1024 blocks: blocks 0..767 -> q/k/v (256 blocks each, 4M elems),
// 768..1023 -> Wq/Wk/Wv/Wo (64 blocks each, 1M elems). 8 iters everywhere.
__global__ __launch_bounds__(256) void cvt_all(
    const float* __restrict__ q, const float* __restrict__ k,
    const float* __restrict__ v, const float* __restrict__ wq,
    const float* __restrict__ wk, const float* __restrict__ wv,
    const float* __restrict__ wo, bf16_t* __restrict__ qb,
    bf16_t* __restrict__ kb, bf16_t* __restrict__ vb,
    bf16_t* __restrict__ wqb, bf16_t* __restrict__ wkb,
    bf16_t* __restrict__ wvb, bf16_t* __restrict__ wob) {
  const int bid = blockIdx.x;
  const float* src;
  bf16_t* dst;
  size_t n;
  int nb, b0;
  if (bid < 768) {
    const int t = bid >> 8;
    b0 = bid & 255; nb = 256;
    src = (t == 0) ? q : (t == 1) ? k : v;
    dst = (t == 0) ? qb : (t == 1) ? kb : vb;
    n = (size_t)Bb * Tt * Dd;
  } else {
    const int t = (bid - 768) >> 6;
    b0 = (bid - 768) & 63; nb = 64;
    src = (t == 0) ? wq : (t == 1) ? wk : (t == 2) ? wv : wo;
    dst = (t == 0) ? wqb : (t == 1) ? wkb : (t == 2) ? wvb : wob;
    n = (size_t)Dd * Dd;
  }
  const size_t stride = (size_t)nb * 256 * 8;
  for (size_t i = ((size_t)b0 * 256 + threadIdx.x) * 8; i < n; i += stride) {
    const float4 a = *(const float4*)(src + i);
    const float4 b2 = *(const float4*)(src + i + 4);
    *(bf16x8*)(dst + i) = cvt8(a, b2);
  }
}

// ---------------- GEMMs: C[M,N] = A[M,K] @ B[N,K]^T + bias ----------------
// m97 structure: pure-bf16 inputs, async16 (global_load_lds dwordx4) staging
// for BOTH operands, 128x128 tile, BK=64, 2-barrier K-loop. Verified-class
// 874-912 TF at this exact shape.
#define GM 4096
#define GN 1024
#define GK 1024

// Fused Q/K/V projections: blockIdx.z selects problem. z==2 (V) writes the
// output TRANSPOSED: Vt[(b*H+h)*DK + dk][t] for coalesced attn staging.
__global__ __launch_bounds__(256) void gemm_qkv_bf16(
    const bf16_t* __restrict__ Aq, const bf16_t* __restrict__ Ak,
    const bf16_t* __restrict__ Av, const bf16_t* __restrict__ Wqb,
    const bf16_t* __restrict__ Wkb, const bf16_t* __restrict__ Wvb,
    const float* __restrict__ bqp, const float* __restrict__ bkp,
    const float* __restrict__ bvp, bf16_t* __restrict__ Cq,
    bf16_t* __restrict__ Ck, bf16_t* __restrict__ Cv) {
  __shared__ bf16_t As[128 * 64];
  __shared__ bf16_t Bs[128 * 64];
  const int z = blockIdx.z;
  const bf16_t* A = (z == 0) ? Aq : (z == 1) ? Ak : Av;
  const bf16_t* Bw = (z == 0) ? Wqb : (z == 1) ? Wkb : Wvb;
  const float* bias = (z == 0) ? bqp : (z == 1) ? bkp : bvp;

  const int tid = threadIdx.x;
  const int lane = tid & 63;
  const int w = tid >> 6;
  const int wy = w >> 1, wx = w & 1;
  const int m0 = blockIdx.y * 128, n0 = blockIdx.x * 128;
  const int q = lane >> 4, cc = lane & 15;
  const int srow = lane >> 3;          // 0..7 within 8-row slab
  const int scol = (lane & 7) * 8;     // elem offset in row

  f32x4 acc[4][4] = {};

  for (int k0 = 0; k0 < GK; k0 += 64) {
    __syncthreads();
#pragma unroll
    for (int i = 0; i < 4; ++i) {
      const int r0 = w * 32 + i * 8;   // wave w stages rows r0..r0+7
      async16(A + (size_t)(m0 + r0 + srow) * GK + k0 + scol, As + r0 * 64);
      async16(Bw + (size_t)(n0 + r0 + srow) * GK + k0 + scol, Bs + r0 * 64);
    }
    __syncthreads();
#pragma unroll
    for (int kk = 0; kk < 2; ++kk) {
      bf16x8 af[4], bfr[4];
#pragma unroll
      for (int i = 0; i < 4; ++i)
        af[i] = *(const bf16x8*)(As + (wy * 64 + i * 16 + cc) * 64 + kk * 32 + q * 8);
#pragma unroll
      for (int j = 0; j < 4; ++j)
        bfr[j] = *(const bf16x8*)(Bs + (wx * 64 + j * 16 + cc) * 64 + kk * 32 + q * 8);
#pragma unroll
      for (int i = 0; i < 4; ++i)
#pragma unroll
        for (int j = 0; j < 4; ++j)
          acc[i][j] = __builtin_amdgcn_mfma_f32_16x16x32_bf16(af[i], bfr[j], acc[i][j], 0, 0, 0);
    }
  }

  if (z < 2) {
    bf16_t* C = z ? Ck : Cq;
#pragma unroll
    for (int j = 0; j < 4; ++j) {
      const int col = n0 + wx * 64 + j * 16 + cc;
      const float bv = bias[col];
#pragma unroll
      for (int i = 0; i < 4; ++i) {
        const int row = m0 + wy * 64 + i * 16 + q * 4;
#pragma unroll
        for (int r = 0; r < 4; ++r)
          C[(size_t)(row + r) * GN + col] = (bf16_t)(acc[i][j][r] + bv);
      }
    }
  } else {
    const int bdx = m0 >> 11;                 // batch index
    const int t00 = (m0 & (Tt - 1)) + wy * 64;
#pragma unroll
    for (int j = 0; j < 4; ++j) {
      const int col = n0 + wx * 64 + j * 16 + cc;   // h*64 + dk
      const float bv = bias[col];
      const size_t rowbase = ((size_t)(bdx * Dd + col)) * Tt;
#pragma unroll
      for (int i = 0; i < 4; ++i) {
        const int t0 = t00 + i * 16 + q * 4;
        bf16x4 pk;
#pragma unroll
        for (int r = 0; r < 4; ++r) pk[r] = (bf16_t)(acc[i][j][r] + bv);
        *(bf16x4*)(Cv + rowbase + t0) = pk;
      }
    }
  }
}

// O-projection: identical structure, single problem, plain epilogue.
__global__ __launch_bounds__(256) void gemm_bt_bf16(
    const bf16_t* __restrict__ A, const bf16_t* __restrict__ Bw,
    const float* __restrict__ bias, bf16_t* __restrict__ C) {
  __shared__ bf16_t As[128 * 64];
  __shared__ bf16_t Bs[128 * 64];
  const int tid = threadIdx.x;
  const int lane = tid & 63;
  const int w = tid >> 6;
  const int wy = w >> 1, wx = w & 1;
  const int m0 = blockIdx.y * 128, n0 = blockIdx.x * 128;
  const int q = lane >> 4, cc = lane & 15;
  const int srow = lane >> 3;
  const int scol = (lane & 7) * 8;

  f32x4 acc[4][4] = {};

  for (int k0 = 0; k0 < GK; k0 += 64) {
    __syncthreads();
#pragma unroll
    for (int i = 0; i < 4; ++i) {
      const int r0 = w * 32 + i * 8;
      async16(A + (size_t)(m0 + r0 + srow) * GK + k0 + scol, As + r0 * 64);
      async16(Bw + (size_t)(n0 + r0 + srow) * GK + k0 + scol, Bs + r0 * 64);
    }
    __syncthreads();
#pragma unroll
    for (int kk = 0; kk < 2; ++kk) {
      bf16x8 af[4], bfr[4];
#pragma unroll
      for (int i = 0; i < 4; ++i)
        af[i] = *(const bf16x8*)(As + (wy * 64 + i * 16 + cc) * 64 + kk * 32 + q * 8);
#pragma unroll
      for (int j = 0; j < 4; ++j)
        bfr[j] = *(const bf16x8*)(Bs + (wx * 64 + j * 16 + cc) * 64 + kk * 32 + q * 8);
#pragma unroll
      for (int i = 0; i < 4; ++i)
#pragma unroll
        for (int j = 0; j < 4; ++j)
          acc[i][j] = __builtin_amdgcn_mfma_f32_16x16x32_bf16(af[i], bfr[j], acc[i][j], 0, 0, 0);
    }
  }

#pragma unroll
  for (int j = 0; j < 4; ++j) {
    const int col = n0 + wx * 64 + j * 16 + cc;
    const float bv = bias[col];
#pragma unroll
    for (int i = 0; i < 4; ++i) {
      const int row = m0 + wy * 64 + i * 16 + q * 4;
#pragma unroll
      for (int r = 0; r < 4; ++r)
        C[(size_t)(row + r) * GN + col] = (bf16_t)(acc[i][j][r] + bv);
    }
  }
}

// ---------------- fused attention ----------------
// grid (T/64, H, B), 256 thr.  2-pass, single top barrier per kt, dbuf K/V,
// T2-swizzled LDS, deferred softmax (shift C=8, exact).
// Pass 2: after QK^T the retired K buffer (8KB) is reused as a per-wave fp32
// S half-tile (32 cols at a time): coalesced dwordx4 attn stores + PV A-frag
// read from it (same bf16 rounding as before). LDS = 40KB -> 4 blocks/CU.
__global__ __launch_bounds__(256) void attn_fused(
    const bf16_t* __restrict__ Qm, const bf16_t* __restrict__ Km,
    const bf16_t* __restrict__ Vt_g,   // [B*H*DK][T] bf16 (pre-transposed)
    float* __restrict__ attn_out,      // [B,H,T,T] fp32
    bf16_t* __restrict__ Xb) {         // [B,T,D] bf16
  __shared__ bf16_t Qs[64 * 64];
  __shared__ bf16_t Ks[2][64 * 64];
  __shared__ bf16_t Vs[2][64 * 64];    // V^T tile: [d][k]

  const int tid = threadIdx.x;
  const int lane = tid & 63;
  const int w = tid >> 6;
  const int qt = blockIdx.x, h = blockIdx.y, b = blockIdx.z;
  const int q = lane >> 4, cc = lane & 15;
  const size_t base = (size_t)b * Tt * Dd + (size_t)h * DKk;
  const size_t vbase = ((size_t)(b * Hh + h) * DKk) * Tt;
  const int srow = lane >> 3;                   // 0..7 within 8-row slab
  const int gcol = ((lane & 7) ^ srow) * 8;     // pre-swizzled src chunk (elems)
  const int l2 = lane >> 2;                     // 0..15: row16 for readback
  const int lc = lane & 3;                      // chunk base for readback
  const float CL = 0.18033688f;   // 0.125 * log2(e)
  const float C2 = 11.54156028f;  // 8 * log2(e)

  // prologue: stage Q tile + K tile 0
#pragma unroll
  for (int i = 0; i < 2; ++i) {
    const int r0 = w * 16 + i * 8;
    async16(Qm + base + (size_t)(qt * 64 + r0 + srow) * Dd + gcol, Qs + r0 * 64);
    async16(Km + base + (size_t)(r0 + srow) * Dd + gcol, Ks[0] + r0 * 64);
  }

  float Mp[4], Lp[4];
#pragma unroll
  for (int r = 0; r < 4; ++r) { Mp[r] = -3.0e38f; Lp[r] = 0.f; }

  // ---- pass 1: per-lane max / sum-exp only ----
  for (int kt = 0; kt < 32; ++kt) {
    __syncthreads();
    if (kt < 31) {
      bf16_t* kd = Ks[(kt + 1) & 1];
#pragma unroll
      for (int i = 0; i < 2; ++i) {
        const int r0 = w * 16 + i * 8;
        async16(Km + base + (size_t)((kt + 1) * 64 + r0 + srow) * Dd + gcol, kd + r0 * 64);
      }
    }
    const bf16_t* kc = Ks[kt & 1];
    f32x4 acc[4] = {};
    __builtin_amdgcn_s_setprio(1);
#pragma unroll
    for (int kk = 0; kk < 2; ++kk) {
      const bf16x8 af = LDSW(Qs, w * 16 + cc, kk * 4 + q);
#pragma unroll
      for (int j = 0; j < 4; ++j) {
        const bf16x8 bfr = LDSW(kc, j * 16 + cc, kk * 4 + q);
        acc[j] = __builtin_amdgcn_mfma_f32_16x16x32_bf16(af, bfr, acc[j], 0, 0, 0);
      }
    }
    __builtin_amdgcn_s_setprio(0);
#pragma unroll
    for (int r = 0; r < 4; ++r) {
      Mp[r] = fmaxf(Mp[r], fmaxf(fmaxf(acc[0][r], acc[1][r]),
                                 fmaxf(acc[2][r], acc[3][r])));
      Lp[r] += exp2f(fmaf(acc[0][r], CL, -C2)) + exp2f(fmaf(acc[1][r], CL, -C2)) +
               exp2f(fmaf(acc[2][r], CL, -C2)) + exp2f(fmaf(acc[3][r], CL, -C2));
    }
  }

  float inv1[4];
#pragma unroll
  for (int r = 0; r < 4; ++r) {
    float mx = Mp[r];
#pragma unroll
    for (int msk = 1; msk < 16; msk <<= 1) mx = fmaxf(mx, __shfl_xor(mx, msk));
    float ls = Lp[r];
#pragma unroll
    for (int msk = 1; msk < 16; msk <<= 1) ls += __shfl_xor(ls, msk);
    inv1[r] = 1.0f / (exp2f(fmaf(mx, CL, -C2)) + ls);
  }

  // prologue pass 2: K tile 0 + V^T tile 0
#pragma unroll
  for (int i = 0; i < 2; ++i) {
    const int r0 = w * 16 + i * 8;
    async16(Km + base + (size_t)(r0 + srow) * Dd + gcol, Ks[0] + r0 * 64);
    async16(Vt_g + vbase + (size_t)(r0 + srow) * Tt + gcol, Vs[0] + r0 * 64);
  }

  f32x4 xacc[4] = {};
  const size_t arowbase = ((size_t)(b * Hh + h) * Tt + (size_t)qt * 64) * Tt;

  // ---- pass 2 ----
  for (int kt = 0; kt < 32; ++kt) {
    __syncthreads();
    if (kt < 31) {
      bf16_t* kd = Ks[(kt + 1) & 1];
      bf16_t* vd = Vs[(kt + 1) & 1];
#pragma unroll
      for (int i = 0; i < 2; ++i) {
        const int r0 = w * 16 + i * 8;
        async16(Km + base + (size_t)((kt + 1) * 64 + r0 + srow) * Dd + gcol, kd + r0 * 64);
        async16(Vt_g + vbase + (size_t)(r0 + srow) * Tt + (kt + 1) * 64 + gcol, vd + r0 * 64);
      }
    }
    const bf16_t* kc = Ks[kt & 1];
    const bf16_t* vc = Vs[kt & 1];

    f32x4 acc[4] = {};
    __builtin_amdgcn_s_setprio(1);
#pragma unroll
    for (int kk = 0; kk < 2; ++kk) {
      const bf16x8 af = LDSW(Qs, w * 16 + cc, kk * 4 + q);
#pragma unroll
      for (int j = 0; j < 4; ++j) {
        const bf16x8 bfr = LDSW(kc, j * 16 + cc, kk * 4 + q);
        acc[j] = __builtin_amdgcn_mfma_f32_16x16x32_bf16(af, bfr, acc[j], 0, 0, 0);
      }
    }
    __builtin_amdgcn_s_setprio(0);

    // rendezvous: all waves finished reading kc. Raw barrier (NO vmcnt drain:
    // prefetch stays in flight). Reads are complete (lgkmcnt before MFMA).
    __builtin_amdgcn_sched_barrier(0);
    __builtin_amdgcn_s_barrier();

    // per-wave fp32 S stripe in the retired kc buffer:
    // stripe = kc + w*2048, layout [16 rows][32 f32], byte swizzle
    // lb ^ ((row16&7)<<4) at 16B granularity (2-way conflicts max).
    char* sfw = (char*)(&Ks[kt & 1][0]) + w * 2048;
#pragma unroll
    for (int half = 0; half < 2; ++half) {
      // write 8 S values (cols half*32 .. +31)
#pragma unroll
      for (int jj = 0; jj < 2; ++jj) {
        const int j = half * 2 + jj;
#pragma unroll
        for (int r = 0; r < 4; ++r) {
          const int row16 = q * 4 + r;
          const float p = exp2f(fmaf(acc[j][r], CL, -C2)) * inv1[r];
          *(float*)(sfw + row16 * 128 +
                    (((jj * 16 + cc) * 4) ^ ((row16 & 7) << 4))) = p;
        }
      }
      // coalesced readback + dwordx4 attn store (own stripe, DS in-order)
#pragma unroll
      for (int s = 0; s < 2; ++s) {
        const int ch = lc + 4 * s;  // 16B chunk 0..7 within 128B row
        const f32x4 v = *(const f32x4*)(sfw + l2 * 128 +
                                        ((ch * 16) ^ ((l2 & 7) << 4)));
        const int prow = w * 16 + l2;
        *(f32x4*)(attn_out + arowbase + (size_t)prow * Tt + kt * 64 +
                  half * 32 + ch * 4) = v;
      }
      // PV for kk = half: A-frag from fp32 stripe (row = cc), cvt to bf16
      const char* p0 = sfw + cc * 128;
      const f32x4 a = *(const f32x4*)(p0 + ((q * 32) ^ ((cc & 7) << 4)));
      const f32x4 bb = *(const f32x4*)(p0 + ((q * 32 + 16) ^ ((cc & 7) << 4)));
      bf16x8 af;
      af[0] = (bf16_t)a[0]; af[1] = (bf16_t)a[1];
      af[2] = (bf16_t)a[2]; af[3] = (bf16_t)a[3];
      af[4] = (bf16_t)bb[0]; af[5] = (bf16_t)bb[1];
      af[6] = (bf16_t)bb[2]; af[7] = (bf16_t)bb[3];
      __builtin_amdgcn_s_setprio(1);
#pragma unroll
      for (int j = 0; j < 4; ++j) {
        const bf16x8 bfr = LDSW(vc, j * 16 + cc, half * 4 + q);
        xacc[j] = __builtin_amdgcn_mfma_f32_16x16x32_bf16(af, bfr, xacc[j], 0, 0, 0);
      }
      __builtin_amdgcn_s_setprio(0);
    }
  }

#pragma unroll
  for (int j = 0; j < 4; ++j)
#pragma unroll
    for (int r = 0; r < 4; ++r) {
      const int row = qt * 64 + w * 16 + q * 4 + r;
      Xb[base + (size_t)row * Dd + j * 16 + cc] = (bf16_t)xacc[j][r];
    }
}

// ---------------- residual + LayerNorm (fp32 out) ----------------
__global__ __launch_bounds__(256) void ln_kernel(
    const float* __restrict__ resid, const bf16_t* __restrict__ O,
    const float* __restrict__ gamma, const float* __restrict__ beta,
    float* __restrict__ out) {
  const int row = blockIdx.x;
  const int tid = threadIdx.x;
  const size_t roff = (size_t)row * Dd + tid * 4;
  const float4 rv = *(const float4*)(resid + roff);
  const bf16x4 ov = *(const bf16x4*)(O + roff);
  const float y0 = rv.x + (float)ov.x;
  const float y1 = rv.y + (float)ov.y;
  const float y2 = rv.z + (float)ov.z;
  const float y3 = rv.w + (float)ov.w;
  float s = y0 + y1 + y2 + y3;
  float s2 = y0 * y0 + y1 * y1 + y2 * y2 + y3 * y3;
#pragma unroll
  for (int msk = 1; msk < 64; msk <<= 1) {
    s += __shfl_xor(s, msk);
    s2 += __shfl_xor(s2, msk);
  }
  __shared__ float red[8];
  const int w = tid >> 6;
  if ((tid & 63) == 0) { red[w] = s; red[4 + w] = s2; }
  __syncthreads();
  s = red[0] + red[1] + red[2] + red[3];
  s2 = red[4] + red[5] + red[6] + red[7];
  const float mu = s * (1.f / Dd);
  const float rstd = rsqrtf(s2 * (1.f / Dd) - mu * mu + 1e-5f);
  const float4 gv = *(const float4*)(gamma + tid * 4);
  const float4 bv = *(const float4*)(beta + tid * 4);
  float4 o;
  o.x = (y0 - mu) * rstd * gv.x + bv.x;
  o.y = (y1 - mu) * rstd * gv.y + bv.y;
  o.z = (y2 - mu) * rstd * gv.z + bv.z;
  o.w = (y3 - mu) * rstd * gv.w + bv.w;
  *(float4*)(out + roff) = o;
}

extern "C" void kernel_launch(void* const* d_in, const int* in_sizes, int n_in,
                              void* d_out, int out_size, void* d_ws, size_t ws_size,
                              hipStream_t stream) {
  const float* query = (const float*)d_in[0];
  const float* key = (const float*)d_in[1];
  const float* value = (const float*)d_in[2];
  const float* Wq = (const float*)d_in[3];
  const float* bq = (const float*)d_in[4];
  const float* Wk = (const float*)d_in[5];
  const float* bk = (const float*)d_in[6];
  const float* Wv = (const float*)d_in[7];
  const float* bv = (const float*)d_in[8];
  const float* Wo = (const float*)d_in[9];
  const float* bo = (const float*)d_in[10];
  const float* gamma = (const float*)d_in[11];
  const float* beta = (const float*)d_in[12];

  float* y_out = (float*)d_out;                       // [B,T,D] fp32
  float* attn_out = y_out + (size_t)Bb * Tt * Dd;     // [B,H,T,T] fp32

  // workspace: 8x bf16 [B,T,D] (64MB) + 4x bf16 [D,D] (8MB) = 72MB
  char* p = (char*)d_ws;
  const size_t nTD = (size_t)Bb * Tt * Dd;  // 4,194,304
  const size_t nDD = (size_t)Dd * Dd;       // 1,048,576
  bf16_t* Qb = (bf16_t*)p;   p += nTD * 2;
  bf16_t* Kb = (bf16_t*)p;   p += nTD * 2;
  bf16_t* VtG = (bf16_t*)p;  p += nTD * 2;  // [B*H*DK][T]
  bf16_t* Xb = (bf16_t*)p;   p += nTD * 2;
  bf16_t* Ob = (bf16_t*)p;   p += nTD * 2;
  bf16_t* Qin = (bf16_t*)p;  p += nTD * 2;
  bf16_t* Kin = (bf16_t*)p;  p += nTD * 2;
  bf16_t* Vin = (bf16_t*)p;  p += nTD * 2;
  bf16_t* Wqb = (bf16_t*)p;  p += nDD * 2;
  bf16_t* Wkb = (bf16_t*)p;  p += nDD * 2;
  bf16_t* Wvb = (bf16_t*)p;  p += nDD * 2;
  bf16_t* Wob = (bf16_t*)p;  p += nDD * 2;

  cvt_all<<<1024, 256, 0, stream>>>(query, key, value, Wq, Wk, Wv, Wo,
                                    Qin, Kin, Vin, Wqb, Wkb, Wvb, Wob);

  dim3 gqkv(GN / 128, GM / 128, 3);  // (8, 32, 3) = 768 blocks
  gemm_qkv_bf16<<<gqkv, 256, 0, stream>>>(Qin, Kin, Vin, Wqb, Wkb, Wvb,
                                          bq, bk, bv, Qb, Kb, VtG);

  dim3 ga(Tt / 64, Hh, Bb);  // (32, 16, 2)
  attn_fused<<<ga, 256, 0, stream>>>(Qb, Kb, VtG, attn_out, Xb);

  dim3 go(GN / 128, GM / 128);  // (8, 32) = 256 blocks
  gemm_bt_bf16<<<go, 256, 0, stream>>>(Xb, Wob, bo, Ob);

  ln_kernel<<<Bb * Tt, 256, 0, stream>>>(query, Ob, gamma, beta, y_out);
}

// Round 8
// 841.094 us; speedup vs baseline: 1.0961x; 1.0031x over previous
//
#include <hip/hip_runtime.h>
#include <hip/hip_bf16.h>
#include <math.h>

#define Bb 2
#define Tt 2048
#define Dd 1024
#define Hh 16
#define DKk 64

typedef __bf16 bf16_t;
typedef __bf16 bf16x8 __attribute__((ext_vector_type(8)));
typedef __bf16 bf16x4 __attribute__((ext_vector_type(4)));
typedef float f32x4 __attribute__((ext_vector_type(4)));

// async global->LDS, 16B per lane. LDS dest = wave-uniform base + lane*16.
__device__ __forceinline__ void async16(const void* gsrc, void* ldst) {
  void* g = const_cast<void*>(gsrc);
  __builtin_amdgcn_global_load_lds(
      (__attribute__((address_space(1))) void*)g,
      (__attribute__((address_space(3))) void*)ldst, 16, 0, 0);
}

__device__ __forceinline__ bf16x8 cvt8(const float4 a, const float4 b) {
  bf16x8 o;
  o[0] = (bf16_t)a.x; o[1] = (bf16_t)a.y; o[2] = (bf16_t)a.z; o[3] = (bf16_t)a.w;
  o[4] = (bf16_t)b.x; o[5] = (bf16_t)b.y; o[6] = (bf16_t)b.z; o[7] = (bf16_t)b.w;
  return o;
}

// swizzled LDS b128 fragment read: 64x64 bf16 tile, row stride 128B,
// 16B-chunk index ch (0..7) XORed with (row&7)  [T2 st-style swizzle]
#define LDSW(p, row, ch) \
  (*(const bf16x8*)((const char*)(p) + (row) * 128 + ((((ch) ^ (row)) & 7) << 4)))

// ---------------- fp32 -> bf16 conversion (inputs + weights) ----------------
__global__ __launch_bounds__(256) void cvt_all(
    const float* __restrict__ q, const float* __restrict__ k,
    const float* __restrict__ v, const float* __restrict__ wq,
    const float* __restrict__ wk, const float* __restrict__ wv,
    const float* __restrict__ wo, bf16_t* __restrict__ qb,
    bf16_t* __restrict__ kb, bf16_t* __restrict__ vb,
    bf16_t* __restrict__ wqb, bf16_t* __restrict__ wkb,
    bf16_t* __restrict__ wvb, bf16_t* __restrict__ wob) {
  const int bid = blockIdx.x;
  const float* src;
  bf16_t* dst;
  size_t n;
  int nb, b0;
  if (bid < 768) {
    const int t = bid >> 8;
    b0 = bid & 255; nb = 256;
    src = (t == 0) ? q : (t == 1) ? k : v;
    dst = (t == 0) ? qb : (t == 1) ? kb : vb;
    n = (size_t)Bb * Tt * Dd;
  } else {
    const int t = (bid - 768) >> 6;
    b0 = (bid - 768) & 63; nb = 64;
    src = (t == 0) ? wq : (t == 1) ? wk : (t == 2) ? wv : wo;
    dst = (t == 0) ? wqb : (t == 1) ? wkb : (t == 2) ? wvb : wob;
    n = (size_t)Dd * Dd;
  }
  const size_t stride = (size_t)nb * 256 * 8;
  for (size_t i = ((size_t)b0 * 256 + threadIdx.x) * 8; i < n; i += stride) {
    const float4 a = *(const float4*)(src + i);
    const float4 b2 = *(const float4*)(src + i + 4);
    *(bf16x8*)(dst + i) = cvt8(a, b2);
  }
}

// ---------------- GEMMs: C[M,N] = A[M,K] @ B[N,K]^T + bias ----------------
#define GM 4096
#define GN 1024
#define GK 1024

// Fused Q/K/V projections (128x128 tile, verified R7). z==2 (V) writes the
// output TRANSPOSED: Vt[(b*H+h)*DK + dk][t] for coalesced attn staging.
__global__ __launch_bounds__(256) void gemm_qkv_bf16(
    const bf16_t* __restrict__ Aq, const bf16_t* __restrict__ Ak,
    const bf16_t* __restrict__ Av, const bf16_t* __restrict__ Wqb,
    const bf16_t* __restrict__ Wkb, const bf16_t* __restrict__ Wvb,
    const float* __restrict__ bqp, const float* __restrict__ bkp,
    const float* __restrict__ bvp, bf16_t* __restrict__ Cq,
    bf16_t* __restrict__ Ck, bf16_t* __restrict__ Cv) {
  __shared__ bf16_t As[128 * 64];
  __shared__ bf16_t Bs[128 * 64];
  const int z = blockIdx.z;
  const bf16_t* A = (z == 0) ? Aq : (z == 1) ? Ak : Av;
  const bf16_t* Bw = (z == 0) ? Wqb : (z == 1) ? Wkb : Wvb;
  const float* bias = (z == 0) ? bqp : (z == 1) ? bkp : bvp;

  const int tid = threadIdx.x;
  const int lane = tid & 63;
  const int w = tid >> 6;
  const int wy = w >> 1, wx = w & 1;
  const int m0 = blockIdx.y * 128, n0 = blockIdx.x * 128;
  const int q = lane >> 4, cc = lane & 15;
  const int srow = lane >> 3;          // 0..7 within 8-row slab
  const int scol = (lane & 7) * 8;     // elem offset in row

  f32x4 acc[4][4] = {};

  for (int k0 = 0; k0 < GK; k0 += 64) {
    __syncthreads();
#pragma unroll
    for (int i = 0; i < 4; ++i) {
      const int r0 = w * 32 + i * 8;   // wave w stages rows r0..r0+7
      async16(A + (size_t)(m0 + r0 + srow) * GK + k0 + scol, As + r0 * 64);
      async16(Bw + (size_t)(n0 + r0 + srow) * GK + k0 + scol, Bs + r0 * 64);
    }
    __syncthreads();
#pragma unroll
    for (int kk = 0; kk < 2; ++kk) {
      bf16x8 af[4], bfr[4];
#pragma unroll
      for (int i = 0; i < 4; ++i)
        af[i] = *(const bf16x8*)(As + (wy * 64 + i * 16 + cc) * 64 + kk * 32 + q * 8);
#pragma unroll
      for (int j = 0; j < 4; ++j)
        bfr[j] = *(const bf16x8*)(Bs + (wx * 64 + j * 16 + cc) * 64 + kk * 32 + q * 8);
#pragma unroll
      for (int i = 0; i < 4; ++i)
#pragma unroll
        for (int j = 0; j < 4; ++j)
          acc[i][j] = __builtin_amdgcn_mfma_f32_16x16x32_bf16(af[i], bfr[j], acc[i][j], 0, 0, 0);
    }
  }

  if (z < 2) {
    bf16_t* C = z ? Ck : Cq;
#pragma unroll
    for (int j = 0; j < 4; ++j) {
      const int col = n0 + wx * 64 + j * 16 + cc;
      const float bv = bias[col];
#pragma unroll
      for (int i = 0; i < 4; ++i) {
        const int row = m0 + wy * 64 + i * 16 + q * 4;
#pragma unroll
        for (int r = 0; r < 4; ++r)
          C[(size_t)(row + r) * GN + col] = (bf16_t)(acc[i][j][r] + bv);
      }
    }
  } else {
    const int bdx = m0 >> 11;                 // batch index
    const int t00 = (m0 & (Tt - 1)) + wy * 64;
#pragma unroll
    for (int j = 0; j < 4; ++j) {
      const int col = n0 + wx * 64 + j * 16 + cc;   // h*64 + dk
      const float bv = bias[col];
      const size_t rowbase = ((size_t)(bdx * Dd + col)) * Tt;
#pragma unroll
      for (int i = 0; i < 4; ++i) {
        const int t0 = t00 + i * 16 + q * 4;
        bf16x4 pk;
#pragma unroll
        for (int r = 0; r < 4; ++r) pk[r] = (bf16_t)(acc[i][j][r] + bv);
        *(bf16x4*)(Cv + rowbase + t0) = pk;
      }
    }
  }
}

// O-projection: BM=64 x BN=128 -> grid (8,64) = 512 blocks (2/CU) so barrier
// drains overlap across co-resident blocks. bf16 async16 staging both operands.
__global__ __launch_bounds__(256) void gemm_bt_bf16_64(
    const bf16_t* __restrict__ A, const bf16_t* __restrict__ Bw,
    const float* __restrict__ bias, bf16_t* __restrict__ C) {
  __shared__ bf16_t As[64 * 64];
  __shared__ bf16_t Bs[128 * 64];
  const int tid = threadIdx.x;
  const int lane = tid & 63;
  const int w = tid >> 6;
  const int wy = w >> 1, wx = w & 1;
  const int m0 = blockIdx.y * 64, n0 = blockIdx.x * 128;
  const int q = lane >> 4, cc = lane & 15;
  const int srow = lane >> 3;
  const int scol = (lane & 7) * 8;

  f32x4 acc[2][4] = {};

  for (int k0 = 0; k0 < GK; k0 += 64) {
    __syncthreads();
#pragma unroll
    for (int i = 0; i < 2; ++i) {      // A: 16 rows/wave (64 total)
      const int r0 = w * 16 + i * 8;
      async16(A + (size_t)(m0 + r0 + srow) * GK + k0 + scol, As + r0 * 64);
    }
#pragma unroll
    for (int i = 0; i < 4; ++i) {      // B: 32 rows/wave (128 total)
      const int r0 = w * 32 + i * 8;
      async16(Bw + (size_t)(n0 + r0 + srow) * GK + k0 + scol, Bs + r0 * 64);
    }
    __syncthreads();
#pragma unroll
    for (int kk = 0; kk < 2; ++kk) {
      bf16x8 af[2], bfr[4];
#pragma unroll
      for (int i = 0; i < 2; ++i)
        af[i] = *(const bf16x8*)(As + (wy * 32 + i * 16 + cc) * 64 + kk * 32 + q * 8);
#pragma unroll
      for (int j = 0; j < 4; ++j)
        bfr[j] = *(const bf16x8*)(Bs + (wx * 64 + j * 16 + cc) * 64 + kk * 32 + q * 8);
#pragma unroll
      for (int i = 0; i < 2; ++i)
#pragma unroll
        for (int j = 0; j < 4; ++j)
          acc[i][j] = __builtin_amdgcn_mfma_f32_16x16x32_bf16(af[i], bfr[j], acc[i][j], 0, 0, 0);
    }
  }

#pragma unroll
  for (int j = 0; j < 4; ++j) {
    const int col = n0 + wx * 64 + j * 16 + cc;
    const float bv = bias[col];
#pragma unroll
    for (int i = 0; i < 2; ++i) {
      const int row = m0 + wy * 32 + i * 16 + q * 4;
#pragma unroll
      for (int r = 0; r < 4; ++r)
        C[(size_t)(row + r) * GN + col] = (bf16_t)(acc[i][j][r] + bv);
    }
  }
}

// ---------------- fused attention ----------------
// grid (T/64, H, B), 256 thr.  2-pass, single top barrier per kt, dbuf K/V,
// T2-swizzled LDS, deferred softmax (shift C=8, exact).
// NEW: Q fragments are loop-invariant -> hoisted into 8 VGPRs once (removes
// 8KB/block/kt of LDS reads in BOTH passes; attn is LDS-pipe-bound).
__global__ __launch_bounds__(256) void attn_fused(
    const bf16_t* __restrict__ Qm, const bf16_t* __restrict__ Km,
    const bf16_t* __restrict__ Vt_g,   // [B*H*DK][T] bf16 (pre-transposed)
    float* __restrict__ attn_out,      // [B,H,T,T] fp32
    bf16_t* __restrict__ Xb) {         // [B,T,D] bf16
  __shared__ bf16_t Qs[64 * 64];
  __shared__ bf16_t Ks[2][64 * 64];
  __shared__ bf16_t Vs[2][64 * 64];    // V^T tile: [d][k]

  const int tid = threadIdx.x;
  const int lane = tid & 63;
  const int w = tid >> 6;
  const int qt = blockIdx.x, h = blockIdx.y, b = blockIdx.z;
  const int q = lane >> 4, cc = lane & 15;
  const size_t base = (size_t)b * Tt * Dd + (size_t)h * DKk;
  const size_t vbase = ((size_t)(b * Hh + h) * DKk) * Tt;
  const int srow = lane >> 3;                   // 0..7 within 8-row slab
  const int gcol = ((lane & 7) ^ srow) * 8;     // pre-swizzled src chunk (elems)
  const int l2 = lane >> 2;                     // 0..15: row16 for readback
  const int lc = lane & 3;                      // chunk base for readback
  const float CL = 0.18033688f;   // 0.125 * log2(e)
  const float C2 = 11.54156028f;  // 8 * log2(e)

  // prologue: stage Q tile + K tile 0
#pragma unroll
  for (int i = 0; i < 2; ++i) {
    const int r0 = w * 16 + i * 8;
    async16(Qm + base + (size_t)(qt * 64 + r0 + srow) * Dd + gcol, Qs + r0 * 64);
    async16(Km + base + (size_t)(r0 + srow) * Dd + gcol, Ks[0] + r0 * 64);
  }
  __syncthreads();  // drain prologue; Qs ready
  // Q fragments: loop-invariant, read ONCE (used in both passes)
  const bf16x8 qf0 = LDSW(Qs, w * 16 + cc, q);      // kk=0
  const bf16x8 qf1 = LDSW(Qs, w * 16 + cc, 4 + q);  // kk=1

  float Mp[4], Lp[4];
#pragma unroll
  for (int r = 0; r < 4; ++r) { Mp[r] = -3.0e38f; Lp[r] = 0.f; }

  // ---- pass 1: per-lane max / sum-exp only ----
  for (int kt = 0; kt < 32; ++kt) {
    __syncthreads();
    if (kt < 31) {
      bf16_t* kd = Ks[(kt + 1) & 1];
#pragma unroll
      for (int i = 0; i < 2; ++i) {
        const int r0 = w * 16 + i * 8;
        async16(Km + base + (size_t)((kt + 1) * 64 + r0 + srow) * Dd + gcol, kd + r0 * 64);
      }
    }
    const bf16_t* kc = Ks[kt & 1];
    f32x4 acc[4] = {};
    __builtin_amdgcn_s_setprio(1);
#pragma unroll
    for (int kk = 0; kk < 2; ++kk) {
      const bf16x8 af = kk ? qf1 : qf0;
#pragma unroll
      for (int j = 0; j < 4; ++j) {
        const bf16x8 bfr = LDSW(kc, j * 16 + cc, kk * 4 + q);
        acc[j] = __builtin_amdgcn_mfma_f32_16x16x32_bf16(af, bfr, acc[j], 0, 0, 0);
      }
    }
    __builtin_amdgcn_s_setprio(0);
#pragma unroll
    for (int r = 0; r < 4; ++r) {
      Mp[r] = fmaxf(Mp[r], fmaxf(fmaxf(acc[0][r], acc[1][r]),
                                 fmaxf(acc[2][r], acc[3][r])));
      Lp[r] += exp2f(fmaf(acc[0][r], CL, -C2)) + exp2f(fmaf(acc[1][r], CL, -C2)) +
               exp2f(fmaf(acc[2][r], CL, -C2)) + exp2f(fmaf(acc[3][r], CL, -C2));
    }
  }

  float inv1[4];
#pragma unroll
  for (int r = 0; r < 4; ++r) {
    float mx = Mp[r];
#pragma unroll
    for (int msk = 1; msk < 16; msk <<= 1) mx = fmaxf(mx, __shfl_xor(mx, msk));
    float ls = Lp[r];
#pragma unroll
    for (int msk = 1; msk < 16; msk <<= 1) ls += __shfl_xor(ls, msk);
    inv1[r] = 1.0f / (exp2f(fmaf(mx, CL, -C2)) + ls);
  }

  // prologue pass 2: K tile 0 + V^T tile 0
#pragma unroll
  for (int i = 0; i < 2; ++i) {
    const int r0 = w * 16 + i * 8;
    async16(Km + base + (size_t)(r0 + srow) * Dd + gcol, Ks[0] + r0 * 64);
    async16(Vt_g + vbase + (size_t)(r0 + srow) * Tt + gcol, Vs[0] + r0 * 64);
  }

  f32x4 xacc[4] = {};
  const size_t arowbase = ((size_t)(b * Hh + h) * Tt + (size_t)qt * 64) * Tt;

  // ---- pass 2 ----
  for (int kt = 0; kt < 32; ++kt) {
    __syncthreads();
    if (kt < 31) {
      bf16_t* kd = Ks[(kt + 1) & 1];
      bf16_t* vd = Vs[(kt + 1) & 1];
#pragma unroll
      for (int i = 0; i < 2; ++i) {
        const int r0 = w * 16 + i * 8;
        async16(Km + base + (size_t)((kt + 1) * 64 + r0 + srow) * Dd + gcol, kd + r0 * 64);
        async16(Vt_g + vbase + (size_t)(r0 + srow) * Tt + (kt + 1) * 64 + gcol, vd + r0 * 64);
      }
    }
    const bf16_t* kc = Ks[kt & 1];
    const bf16_t* vc = Vs[kt & 1];

    f32x4 acc[4] = {};
    __builtin_amdgcn_s_setprio(1);
#pragma unroll
    for (int kk = 0; kk < 2; ++kk) {
      const bf16x8 af = kk ? qf1 : qf0;
#pragma unroll
      for (int j = 0; j < 4; ++j) {
        const bf16x8 bfr = LDSW(kc, j * 16 + cc, kk * 4 + q);
        acc[j] = __builtin_amdgcn_mfma_f32_16x16x32_bf16(af, bfr, acc[j], 0, 0, 0);
      }
    }
    __builtin_amdgcn_s_setprio(0);

    // rendezvous: all waves finished reading kc. Raw barrier (NO vmcnt drain:
    // prefetch stays in flight). Reads are complete (lgkmcnt before MFMA).
    __builtin_amdgcn_sched_barrier(0);
    __builtin_amdgcn_s_barrier();

    // per-wave fp32 S stripe in the retired kc buffer:
    // stripe = kc + w*2048, layout [16 rows][32 f32], byte swizzle
    // lb ^ ((row16&7)<<4) at 16B granularity (2-way conflicts max).
    char* sfw = (char*)(&Ks[kt & 1][0]) + w * 2048;
#pragma unroll
    for (int half = 0; half < 2; ++half) {
      // write 8 S values (cols half*32 .. +31)
#pragma unroll
      for (int jj = 0; jj < 2; ++jj) {
        const int j = half * 2 + jj;
#pragma unroll
        for (int r = 0; r < 4; ++r) {
          const int row16 = q * 4 + r;
          const float p = exp2f(fmaf(acc[j][r], CL, -C2)) * inv1[r];
          *(float*)(sfw + row16 * 128 +
                    (((jj * 16 + cc) * 4) ^ ((row16 & 7) << 4))) = p;
        }
      }
      // coalesced readback + dwordx4 attn store (own stripe, DS in-order)
#pragma unroll
      for (int s = 0; s < 2; ++s) {
        const int ch = lc + 4 * s;  // 16B chunk 0..7 within 128B row
        const f32x4 v = *(const f32x4*)(sfw + l2 * 128 +
                                        ((ch * 16) ^ ((l2 & 7) << 4)));
        const int prow = w * 16 + l2;
        *(f32x4*)(attn_out + arowbase + (size_t)prow * Tt + kt * 64 +
                  half * 32 + ch * 4) = v;
      }
      // PV for kk = half: A-frag from fp32 stripe (row = cc), cvt to bf16
      const char* p0 = sfw + cc * 128;
      const f32x4 a = *(const f32x4*)(p0 + ((q * 32) ^ ((cc & 7) << 4)));
      const f32x4 bb = *(const f32x4*)(p0 + ((q * 32 + 16) ^ ((cc & 7) << 4)));
      bf16x8 af;
      af[0] = (bf16_t)a[0]; af[1] = (bf16_t)a[1];
      af[2] = (bf16_t)a[2]; af[3] = (bf16_t)a[3];
      af[4] = (bf16_t)bb[0]; af[5] = (bf16_t)bb[1];
      af[6] = (bf16_t)bb[2]; af[7] = (bf16_t)bb[3];
      __builtin_amdgcn_s_setprio(1);
#pragma unroll
      for (int j = 0; j < 4; ++j) {
        const bf16x8 bfr = LDSW(vc, j * 16 + cc, half * 4 + q);
        xacc[j] = __builtin_amdgcn_mfma_f32_16x16x32_bf16(af, bfr, xacc[j], 0, 0, 0);
      }
      __builtin_amdgcn_s_setprio(0);
    }
  }

#pragma unroll
  for (int j = 0; j < 4; ++j)
#pragma unroll
    for (int r = 0; r < 4; ++r) {
      const int row = qt * 64 + w * 16 + q * 4 + r;
      Xb[base + (size_t)row * Dd + j * 16 + cc] = (bf16_t)xacc[j][r];
    }
}

// ---------------- residual + LayerNorm (fp32 out) ----------------
__global__ __launch_bounds__(256) void ln_kernel(
    const float* __restrict__ resid, const bf16_t* __restrict__ O,
    const float* __restrict__ gamma, const float* __restrict__ beta,
    float* __restrict__ out) {
  const int row = blockIdx.x;
  const int tid = threadIdx.x;
  const size_t roff = (size_t)row * Dd + tid * 4;
  const float4 rv = *(const float4*)(resid + roff);
  const bf16x4 ov = *(const bf16x4*)(O + roff);
  const float y0 = rv.x + (float)ov.x;
  const float y1 = rv.y + (float)ov.y;
  const float y2 = rv.z + (float)ov.z;
  const float y3 = rv.w + (float)ov.w;
  float s = y0 + y1 + y2 + y3;
  float s2 = y0 * y0 + y1 * y1 + y2 * y2 + y3 * y3;
#pragma unroll
  for (int msk = 1; msk < 64; msk <<= 1) {
    s += __shfl_xor(s, msk);
    s2 += __shfl_xor(s2, msk);
  }
  __shared__ float red[8];
  const int w = tid >> 6;
  if ((tid & 63) == 0) { red[w] = s; red[4 + w] = s2; }
  __syncthreads();
  s = red[0] + red[1] + red[2] + red[3];
  s2 = red[4] + red[5] + red[6] + red[7];
  const float mu = s * (1.f / Dd);
  const float rstd = rsqrtf(s2 * (1.f / Dd) - mu * mu + 1e-5f);
  const float4 gv = *(const float4*)(gamma + tid * 4);
  const float4 bv = *(const float4*)(beta + tid * 4);
  float4 o;
  o.x = (y0 - mu) * rstd * gv.x + bv.x;
  o.y = (y1 - mu) * rstd * gv.y + bv.y;
  o.z = (y2 - mu) * rstd * gv.z + bv.z;
  o.w = (y3 - mu) * rstd * gv.w + bv.w;
  *(float4*)(out + roff) = o;
}

extern "C" void kernel_launch(void* const* d_in, const int* in_sizes, int n_in,
                              void* d_out, int out_size, void* d_ws, size_t ws_size,
                              hipStream_t stream) {
  const float* query = (const float*)d_in[0];
  const float* key = (const float*)d_in[1];
  const float* value = (const float*)d_in[2];
  const float* Wq = (const float*)d_in[3];
  const float* bq = (const float*)d_in[4];
  const float* Wk = (const float*)d_in[5];
  const float* bk = (const float*)d_in[6];
  const float* Wv = (const float*)d_in[7];
  const float* bv = (const float*)d_in[8];
  const float* Wo = (const float*)d_in[9];
  const float* bo = (const float*)d_in[10];
  const float* gamma = (const float*)d_in[11];
  const float* beta = (const float*)d_in[12];

  float* y_out = (float*)d_out;                       // [B,T,D] fp32
  float* attn_out = y_out + (size_t)Bb * Tt * Dd;     // [B,H,T,T] fp32

  // workspace: 8x bf16 [B,T,D] (64MB) + 4x bf16 [D,D] (8MB) = 72MB
  char* p = (char*)d_ws;
  const size_t nTD = (size_t)Bb * Tt * Dd;  // 4,194,304
  const size_t nDD = (size_t)Dd * Dd;       // 1,048,576
  bf16_t* Qb = (bf16_t*)p;   p += nTD * 2;
  bf16_t* Kb = (bf16_t*)p;   p += nTD * 2;
  bf16_t* VtG = (bf16_t*)p;  p += nTD * 2;  // [B*H*DK][T]
  bf16_t* Xb = (bf16_t*)p;   p += nTD * 2;
  bf16_t* Ob = (bf16_t*)p;   p += nTD * 2;
  bf16_t* Qin = (bf16_t*)p;  p += nTD * 2;
  bf16_t* Kin = (bf16_t*)p;  p += nTD * 2;
  bf16_t* Vin = (bf16_t*)p;  p += nTD * 2;
  bf16_t* Wqb = (bf16_t*)p;  p += nDD * 2;
  bf16_t* Wkb = (bf16_t*)p;  p += nDD * 2;
  bf16_t* Wvb = (bf16_t*)p;  p += nDD * 2;
  bf16_t* Wob = (bf16_t*)p;  p += nDD * 2;

  cvt_all<<<1024, 256, 0, stream>>>(query, key, value, Wq, Wk, Wv, Wo,
                                    Qin, Kin, Vin, Wqb, Wkb, Wvb, Wob);

  dim3 gqkv(GN / 128, GM / 128, 3);  // (8, 32, 3) = 768 blocks
  gemm_qkv_bf16<<<gqkv, 256, 0, stream>>>(Qin, Kin, Vin, Wqb, Wkb, Wvb,
                                          bq, bk, bv, Qb, Kb, VtG);

  dim3 ga(Tt / 64, Hh, Bb);  // (32, 16, 2)
  attn_fused<<<ga, 256, 0, stream>>>(Qb, Kb, VtG, attn_out, Xb);

  dim3 go(GN / 128, GM / 64);  // (8, 64) = 512 blocks
  gemm_bt_bf16_64<<<go, 256, 0, stream>>>(Xb, Wob, bo, Ob);

  ln_kernel<<<Bb * Tt, 256, 0, stream>>>(query, Ob, gamma, beta, y_out);
}